// Round 1
// baseline (1093.784 us; speedup 1.0000x reference)
//
#include <hip/hip_runtime.h>
#include <math.h>

#define N_NODES 4096
#define N_EDGES 65536
#define NGRAPH 8
#define LNODE 512
#define NHEAD 4
#define DSTATE 256
#define DINNER 256
#define HEADD 64

__device__ __forceinline__ float softplusf(float z) {
  return (z > 0.0f) ? (z + log1pf(expf(-z))) : log1pf(expf(z));
}

// ---------------------------------------------------------------------------
// Scatter edges into G = A^T (per (graph,head) 512x512), G[l2][l1] += val
// ---------------------------------------------------------------------------
__global__ void scatter_edges_kernel(const float* __restrict__ dt,
                                     const float* __restrict__ dt_edge,
                                     const float* __restrict__ dt_bias,
                                     const int* __restrict__ edge_index,
                                     float* __restrict__ G) {
  int t = blockIdx.x * blockDim.x + threadIdx.x;
  if (t >= N_EDGES * NHEAD) return;
  int e = t >> 2;
  int n = t & 3;
  int src = edge_index[e];
  int dst = edge_index[N_EDGES + e];
  float bias = dt_bias[n];
  float z0 = dt[src * 16 + n * 4 + 0] + bias;
  float z1 = dt[dst * 16 + n * 4 + 1] + bias;
  float z2 = dt_edge[e * 4 + n] + bias;
  float val = expf(-(softplusf(z0) + softplusf(z1) + softplusf(z2)) * (1.0f / 3.0f));
  int b = src >> 9;       // nodes sorted by graph, 512 each
  int l1 = src & 511;
  int l2 = dst & 511;
  atomicAdd(&G[(((size_t)(b * 4 + n)) << 18) + ((size_t)l2 << 9) + l1], val);
}

// ---------------------------------------------------------------------------
// Column-normalize G: col l1 sum (= adj row sum) + dummy -> scale by 1/(norm+tol)
// ---------------------------------------------------------------------------
__global__ void col_normalize_kernel(float* __restrict__ G,
                                     const float* __restrict__ dt,
                                     const float* __restrict__ dt_bias) {
  int c = blockIdx.x * blockDim.x + threadIdx.x;  // 32*512 columns
  int l1 = c & 511;
  int bn = c >> 9;
  int n = bn & 3, b = bn >> 2;
  float* base = G + ((size_t)bn << 18) + l1;
  float ssum = 0.0f;
  for (int l2 = 0; l2 < 512; ++l2) ssum += base[(size_t)l2 << 9];
  float bias = dt_bias[n];
  float dummy = expf(-softplusf(dt[(size_t)(b * 512 + l1) * 16 + n * 4 + 2] + bias));
  float norm = fmaxf(1.0f, ssum + dummy);
  float inv = 1.0f / (norm + 0.05f);
  for (int l2 = 0; l2 < 512; ++l2) base[(size_t)l2 << 9] *= inv;
}

// ---------------------------------------------------------------------------
// Q = I + G (elementwise, float4)
// ---------------------------------------------------------------------------
__global__ void add_identity_kernel(const float* __restrict__ G, float* __restrict__ Q) {
  size_t f = (size_t)blockIdx.x * blockDim.x + threadIdx.x;  // float4 index, 2M total
  size_t base = f << 2;
  float4 v = ((const float4*)G)[f];
  int w = (int)(base & 262143);  // within one 512x512 matrix
  int row = w >> 9, col = w & 511;
  int d = row - col;
  if (d >= 0 && d < 4) ((float*)&v)[d] += 1.0f;
  ((float4*)Q)[f] = v;
}

// ---------------------------------------------------------------------------
// Batched fp32 GEMM: C = A @ B (+ A if ADD_A), 32 x (512x512x512)
// 128x128 tile / 256 threads / 8x8 per thread / BK=16
// ---------------------------------------------------------------------------
template <bool ADD_A>
__global__ __launch_bounds__(256) void gemm512_kernel(const float* __restrict__ A,
                                                      const float* __restrict__ B,
                                                      float* __restrict__ C) {
  const int bn = blockIdx.y;
  const size_t off = (size_t)bn << 18;
  A += off; B += off; C += off;
  const int tile = blockIdx.x;
  const int m0 = (tile >> 2) << 7;
  const int n0 = (tile & 3) << 7;
  __shared__ float As[16][132];
  __shared__ float Bs[16][132];
  const int tid = threadIdx.x;
  const int tx = tid & 15, ty = tid >> 4;
  float acc[8][8] = {};
  for (int k0 = 0; k0 < 512; k0 += 16) {
#pragma unroll
    for (int s = 0; s < 2; ++s) {  // A tile (transposed into LDS)
      int fid = tid + s * 256;
      int m = fid >> 2, kq = fid & 3;
      float4 a = *(const float4*)(A + (size_t)(m0 + m) * 512 + k0 + kq * 4);
      As[kq * 4 + 0][m] = a.x; As[kq * 4 + 1][m] = a.y;
      As[kq * 4 + 2][m] = a.z; As[kq * 4 + 3][m] = a.w;
    }
#pragma unroll
    for (int s = 0; s < 2; ++s) {  // B tile (row-major)
      int fid = tid + s * 256;
      int kk = fid >> 5, nq = fid & 31;
      float4 b = *(const float4*)(B + (size_t)(k0 + kk) * 512 + n0 + nq * 4);
      *(float4*)(&Bs[kk][nq * 4]) = b;
    }
    __syncthreads();
#pragma unroll
    for (int k = 0; k < 16; ++k) {
      float av[8], bv[8];
      *(float4*)(av)     = *(const float4*)(&As[k][ty * 8]);
      *(float4*)(av + 4) = *(const float4*)(&As[k][ty * 8 + 4]);
      *(float4*)(bv)     = *(const float4*)(&Bs[k][tx * 8]);
      *(float4*)(bv + 4) = *(const float4*)(&Bs[k][tx * 8 + 4]);
#pragma unroll
      for (int i = 0; i < 8; ++i)
#pragma unroll
        for (int j = 0; j < 8; ++j)
          acc[i][j] = fmaf(av[i], bv[j], acc[i][j]);
    }
    __syncthreads();
  }
#pragma unroll
  for (int i = 0; i < 8; ++i) {
    size_t row = (size_t)(m0 + ty * 8 + i);
    float* cp = C + row * 512 + n0 + tx * 8;
    if (ADD_A) {
      const float* ap = A + row * 512 + n0 + tx * 8;
      float4 a0 = *(const float4*)ap;
      float4 a1 = *(const float4*)(ap + 4);
      acc[i][0] += a0.x; acc[i][1] += a0.y; acc[i][2] += a0.z; acc[i][3] += a0.w;
      acc[i][4] += a1.x; acc[i][5] += a1.y; acc[i][6] += a1.z; acc[i][7] += a1.w;
    }
    float4 r0 = make_float4(acc[i][0], acc[i][1], acc[i][2], acc[i][3]);
    float4 r1 = make_float4(acc[i][4], acc[i][5], acc[i][6], acc[i][7]);
    *(float4*)cp = r0;
    *(float4*)(cp + 4) = r1;
  }
}

// ---------------------------------------------------------------------------
// S[b] = Cmat[b] @ Bmat[b]^T  (per graph, 512x512x256, NT form)
// ---------------------------------------------------------------------------
__global__ __launch_bounds__(256) void gemm_nt_kernel(const float* __restrict__ Cm,
                                                      const float* __restrict__ Bm,
                                                      float* __restrict__ S) {
  const int b = blockIdx.y;
  const float* Ab = Cm + (size_t)b * LNODE * DSTATE;
  const float* Bb = Bm + (size_t)b * LNODE * DSTATE;
  float* Sb = S + ((size_t)b << 18);
  const int tile = blockIdx.x;
  const int m0 = (tile >> 2) << 7;
  const int n0 = (tile & 3) << 7;
  __shared__ float As[16][132];
  __shared__ float Bs[16][132];
  const int tid = threadIdx.x;
  const int tx = tid & 15, ty = tid >> 4;
  float acc[8][8] = {};
  for (int k0 = 0; k0 < DSTATE; k0 += 16) {
#pragma unroll
    for (int s = 0; s < 2; ++s) {
      int fid = tid + s * 256;
      int m = fid >> 2, kq = fid & 3;
      float4 a = *(const float4*)(Ab + (size_t)(m0 + m) * DSTATE + k0 + kq * 4);
      As[kq * 4 + 0][m] = a.x; As[kq * 4 + 1][m] = a.y;
      As[kq * 4 + 2][m] = a.z; As[kq * 4 + 3][m] = a.w;
      float4 bb = *(const float4*)(Bb + (size_t)(n0 + m) * DSTATE + k0 + kq * 4);
      Bs[kq * 4 + 0][m] = bb.x; Bs[kq * 4 + 1][m] = bb.y;
      Bs[kq * 4 + 2][m] = bb.z; Bs[kq * 4 + 3][m] = bb.w;
    }
    __syncthreads();
#pragma unroll
    for (int k = 0; k < 16; ++k) {
      float av[8], bv[8];
      *(float4*)(av)     = *(const float4*)(&As[k][ty * 8]);
      *(float4*)(av + 4) = *(const float4*)(&As[k][ty * 8 + 4]);
      *(float4*)(bv)     = *(const float4*)(&Bs[k][tx * 8]);
      *(float4*)(bv + 4) = *(const float4*)(&Bs[k][tx * 8 + 4]);
#pragma unroll
      for (int i = 0; i < 8; ++i)
#pragma unroll
        for (int j = 0; j < 8; ++j)
          acc[i][j] = fmaf(av[i], bv[j], acc[i][j]);
    }
    __syncthreads();
  }
#pragma unroll
  for (int i = 0; i < 8; ++i) {
    size_t row = (size_t)(m0 + ty * 8 + i);
    float* sp = Sb + row * 512 + n0 + tx * 8;
    *(float4*)sp = make_float4(acc[i][0], acc[i][1], acc[i][2], acc[i][3]);
    *(float4*)(sp + 4) = make_float4(acc[i][4], acc[i][5], acc[i][6], acc[i][7]);
  }
}

// ---------------------------------------------------------------------------
// M = Lm * dt_self[t] * S[b,l,t]   (in place on Q)
// ---------------------------------------------------------------------------
__global__ void make_M_kernel(float* __restrict__ Q, const float* __restrict__ S,
                              const float* __restrict__ dt) {
  size_t idx = (size_t)blockIdx.x * blockDim.x + threadIdx.x;  // 32*512*512
  int t = (int)(idx & 511);
  size_t r = idx >> 9;
  int l = (int)(r & 511);
  int bn = (int)(r >> 9);
  int n = bn & 3, b = bn >> 2;
  float dts = dt[(size_t)(b * 512 + t) * 16 + n * 4 + 3];
  float s = S[((size_t)b << 18) + ((size_t)l << 9) + t];
  Q[idx] *= dts * s;
}

// ---------------------------------------------------------------------------
// out[(b*512+l)*256 + h*4 + n] = sum_t M[bn][l][t] * x[(b*512+t)*256 + n*64+h]
//                                + x[(b*512+l)*256 + n*64+h] * D[n]
// ---------------------------------------------------------------------------
__global__ __launch_bounds__(256) void final_gemm_kernel(const float* __restrict__ M,
                                                         const float* __restrict__ x,
                                                         const float* __restrict__ Dv,
                                                         float* __restrict__ out) {
  const int bn = blockIdx.y;
  const int n = bn & 3, b = bn >> 2;
  const float* Mb = M + ((size_t)bn << 18);
  const float* xb = x + (size_t)b * LNODE * DINNER + n * HEADD;
  const int m0 = blockIdx.x << 7;
  __shared__ float Ms[16][132];
  __shared__ float Xs[16][64];
  const int tid = threadIdx.x;
  const int tx = tid & 15, ty = tid >> 4;
  float acc[8][4] = {};
  for (int k0 = 0; k0 < 512; k0 += 16) {
#pragma unroll
    for (int s = 0; s < 2; ++s) {
      int fid = tid + s * 256;
      int m = fid >> 2, kq = fid & 3;
      float4 a = *(const float4*)(Mb + (size_t)(m0 + m) * 512 + k0 + kq * 4);
      Ms[kq * 4 + 0][m] = a.x; Ms[kq * 4 + 1][m] = a.y;
      Ms[kq * 4 + 2][m] = a.z; Ms[kq * 4 + 3][m] = a.w;
    }
    {
      int kk = tid >> 4, hq = tid & 15;
      float4 v = *(const float4*)(xb + (size_t)(k0 + kk) * DINNER + hq * 4);
      *(float4*)(&Xs[kk][hq * 4]) = v;
    }
    __syncthreads();
#pragma unroll
    for (int k = 0; k < 16; ++k) {
      float mv[8], xv[4];
      *(float4*)(mv)     = *(const float4*)(&Ms[k][ty * 8]);
      *(float4*)(mv + 4) = *(const float4*)(&Ms[k][ty * 8 + 4]);
      *(float4*)(xv)     = *(const float4*)(&Xs[k][tx * 4]);
#pragma unroll
      for (int i = 0; i < 8; ++i)
#pragma unroll
        for (int j = 0; j < 4; ++j)
          acc[i][j] = fmaf(mv[i], xv[j], acc[i][j]);
    }
    __syncthreads();
  }
  const float Dn = Dv[n];
#pragma unroll
  for (int i = 0; i < 8; ++i) {
    const int l = m0 + ty * 8 + i;
    const float* xrow = x + (size_t)(b * LNODE + l) * DINNER + n * HEADD;
    float* orow = out + (size_t)(b * LNODE + l) * DINNER + n;
#pragma unroll
    for (int j = 0; j < 4; ++j) {
      const int h = tx * 4 + j;
      orow[h * 4] = acc[i][j] + xrow[h] * Dn;
    }
  }
}

// ---------------------------------------------------------------------------
extern "C" void kernel_launch(void* const* d_in, const int* in_sizes, int n_in,
                              void* d_out, int out_size, void* d_ws, size_t ws_size,
                              hipStream_t stream) {
  const float* x        = (const float*)d_in[0];
  const float* Bmat     = (const float*)d_in[1];
  const float* Cmat     = (const float*)d_in[2];
  const float* dt       = (const float*)d_in[3];
  const float* dt_edge  = (const float*)d_in[4];
  const float* dt_bias  = (const float*)d_in[5];
  const float* Dv       = (const float*)d_in[6];
  const int* edge_index = (const int*)d_in[7];
  // d_in[8] data_batch implied by node ordering; d_in[9] diameter==32 -> 4 doubling iters
  float* out = (float*)d_out;
  float* ws = (float*)d_ws;

  const size_t MAT = (size_t)32 * 512 * 512;  // floats per big buffer
  float* buf0 = ws;                 // G / rotating
  float* buf1 = ws + MAT;
  float* buf2 = ws + 2 * MAT;
  float* Sbuf = ws + 3 * MAT;       // 8*512*512 floats
  // total ws use: (3*32 + 8) * 512*512 * 4B = ~104 MB

  hipMemsetAsync(buf0, 0, MAT * sizeof(float), stream);
  scatter_edges_kernel<<<(N_EDGES * NHEAD) / 256, 256, 0, stream>>>(
      dt, dt_edge, dt_bias, edge_index, buf0);
  col_normalize_kernel<<<64, 256, 0, stream>>>(buf0, dt, dt_bias);
  add_identity_kernel<<<8192, 256, 0, stream>>>(buf0, buf1);
  gemm_nt_kernel<<<dim3(16, 8), 256, 0, stream>>>(Cmat, Bmat, Sbuf);

  // doubling: P holds A^(2^i) chain, Q holds running product
  float* P = buf0;
  float* Q = buf1;
  float* F = buf2;
  for (int it = 0; it < 4; ++it) {
    gemm512_kernel<false><<<dim3(16, 32), 256, 0, stream>>>(P, P, F);  // F = P@P
    gemm512_kernel<true><<<dim3(16, 32), 256, 0, stream>>>(Q, F, P);   // P' = Q@F + Q
    float* t = P; P = F; F = Q; Q = t;
  }
  // Q now holds Lm (32 x 512 x 512)

  make_M_kernel<<<32768, 256, 0, stream>>>(Q, Sbuf, dt);
  final_gemm_kernel<<<dim3(4, 32), 256, 0, stream>>>(Q, x, Dv, out);
}

// Round 2
// 421.316 us; speedup vs baseline: 2.5961x; 2.5961x over previous
//
#include <hip/hip_runtime.h>
#include <math.h>

#define N_EDGES 65536
#define LNODE 512
#define DSTATE 256
#define DINNER 256
#define HEADD 64

using bf16x8 = __attribute__((ext_vector_type(8))) short;
using f32x4  = __attribute__((ext_vector_type(4))) float;
using us4    = __attribute__((ext_vector_type(4))) unsigned short;

__device__ __forceinline__ float softplusf(float z) {
  return (z > 0.0f) ? (z + log1pf(expf(-z))) : log1pf(expf(z));
}
__device__ __forceinline__ float bf2f(unsigned short u) {
  unsigned int x = ((unsigned int)u) << 16;
  return __builtin_bit_cast(float, x);
}
__device__ __forceinline__ unsigned short f2bf(float f) {
  unsigned int x = __builtin_bit_cast(unsigned int, f);
  x += 0x7fffu + ((x >> 16) & 1u);
  return (unsigned short)(x >> 16);
}

// ---------------------------------------------------------------------------
// Scatter edges into G = A^T (per (graph,head) 512x512), G[l2][l1] += val
// ---------------------------------------------------------------------------
__global__ void scatter_edges_kernel(const float* __restrict__ dt,
                                     const float* __restrict__ dt_edge,
                                     const float* __restrict__ dt_bias,
                                     const int* __restrict__ edge_index,
                                     float* __restrict__ G) {
  int t = blockIdx.x * blockDim.x + threadIdx.x;
  if (t >= N_EDGES * 4) return;
  int e = t >> 2;
  int n = t & 3;
  int src = edge_index[e];
  int dst = edge_index[N_EDGES + e];
  float bias = dt_bias[n];
  float z0 = dt[src * 16 + n * 4 + 0] + bias;
  float z1 = dt[dst * 16 + n * 4 + 1] + bias;
  float z2 = dt_edge[e * 4 + n] + bias;
  float val = expf(-(softplusf(z0) + softplusf(z1) + softplusf(z2)) * (1.0f / 3.0f));
  int b = src >> 9;
  int l1 = src & 511;
  int l2 = dst & 511;
  atomicAdd(&G[(((size_t)(b * 4 + n)) << 18) + ((size_t)l2 << 9) + l1], val);
}

// ---------------------------------------------------------------------------
// Column-normalize G
// ---------------------------------------------------------------------------
__global__ void col_normalize_kernel(float* __restrict__ G,
                                     const float* __restrict__ dt,
                                     const float* __restrict__ dt_bias) {
  int c = blockIdx.x * blockDim.x + threadIdx.x;  // 32*512 columns
  int l1 = c & 511;
  int bn = c >> 9;
  int n = bn & 3, b = bn >> 2;
  float* base = G + ((size_t)bn << 18) + l1;
  float ssum = 0.0f;
  for (int l2 = 0; l2 < 512; ++l2) ssum += base[(size_t)l2 << 9];
  float bias = dt_bias[n];
  float dummy = expf(-softplusf(dt[(size_t)(b * 512 + l1) * 16 + n * 4 + 2] + bias));
  float norm = fmaxf(1.0f, ssum + dummy);
  float inv = 1.0f / (norm + 0.05f);
  for (int l2 = 0; l2 < 512; ++l2) base[(size_t)l2 << 9] *= inv;
}

// ---------------------------------------------------------------------------
// Convert: Prm = bf16(G), Pt = bf16(G^T), Q = bf16(I + G). 32x32 tiles.
// ---------------------------------------------------------------------------
__global__ __launch_bounds__(256) void conv_kernel(const float* __restrict__ G,
                                                   unsigned short* __restrict__ Prm,
                                                   unsigned short* __restrict__ Pt,
                                                   unsigned short* __restrict__ Q) {
  const int bn = blockIdx.y;
  const size_t base = (size_t)bn << 18;
  const int tile = blockIdx.x;
  const int ro = (tile >> 4) << 5;
  const int co = (tile & 15) << 5;
  __shared__ float lds[32][33];
  const int t = threadIdx.x;
  const int tr = t >> 3;
  const int tc0 = (t & 7) << 2;
  float4 gv = *(const float4*)(G + base + (size_t)(ro + tr) * 512 + co + tc0);
  float vv[4] = {gv.x, gv.y, gv.z, gv.w};
  us4 p, q;
#pragma unroll
  for (int j = 0; j < 4; ++j) {
    p[j] = f2bf(vv[j]);
    float qq = vv[j] + (((ro + tr) == (co + tc0 + j)) ? 1.0f : 0.0f);
    q[j] = f2bf(qq);
    lds[tc0 + j][tr] = vv[j];
  }
  *(us4*)(Prm + base + (size_t)(ro + tr) * 512 + co + tc0) = p;
  *(us4*)(Q + base + (size_t)(ro + tr) * 512 + co + tc0) = q;
  __syncthreads();
  us4 pt;
#pragma unroll
  for (int j = 0; j < 4; ++j) pt[j] = f2bf(lds[tr][tc0 + j]);
  *(us4*)(Pt + base + (size_t)(co + tr) * 512 + ro + tc0) = pt;
}

// ---------------------------------------------------------------------------
// Batched bf16 MFMA GEMM: C = A @ B (+ Qadd), B given transposed ([N][K]).
// 128x128 tile, BK=64, 4 waves (each 64x64), global_load_lds staging with
// XOR-swizzled LDS (swizzle applied on global source + on ds_read address).
// Writes C row-major; optionally also C^T.  32 batches of 512x512x512.
// ---------------------------------------------------------------------------
template <bool WRITE_T, bool ADD>
__global__ __launch_bounds__(256) void gemm_bf16_kernel(
    const unsigned short* __restrict__ A, const unsigned short* __restrict__ Bt,
    unsigned short* __restrict__ Crm, unsigned short* __restrict__ Ct,
    const unsigned short* __restrict__ Qadd) {
  const int bn = blockIdx.y;
  const size_t off = (size_t)bn << 18;
  A += off; Bt += off; Crm += off;
  if (WRITE_T) Ct += off;
  if (ADD) Qadd += off;
  const int m0 = (blockIdx.x >> 2) << 7;
  const int n0 = (blockIdx.x & 3) << 7;
  __shared__ __align__(16) char lds[32768];
  char* ldsA = lds;
  char* ldsB = lds + 16384;
  const int tid = threadIdx.x;
  const int lane = tid & 63;
  const int w = tid >> 6;
  const int wr = w >> 1, wc = w & 1;
  const int lr = lane >> 3, g = lane & 7;

  f32x4 acc[4][4];
#pragma unroll
  for (int i = 0; i < 4; ++i)
#pragma unroll
    for (int j = 0; j < 4; ++j) acc[i][j] = (f32x4)(0.0f);

  for (int k0 = 0; k0 < 512; k0 += 64) {
#pragma unroll
    for (int s = 0; s < 4; ++s) {
      const int r = s * 32 + w * 8 + lr;
      const unsigned short* ga = A + (size_t)(m0 + r) * 512 + k0 + ((g ^ (r & 7)) << 3);
      __builtin_amdgcn_global_load_lds(
          (const __attribute__((address_space(1))) void*)ga,
          (__attribute__((address_space(3))) void*)(ldsA + s * 4096 + w * 1024 + (lane << 4)),
          16, 0, 0);
      const unsigned short* gb = Bt + (size_t)(n0 + r) * 512 + k0 + ((g ^ (r & 7)) << 3);
      __builtin_amdgcn_global_load_lds(
          (const __attribute__((address_space(1))) void*)gb,
          (__attribute__((address_space(3))) void*)(ldsB + s * 4096 + w * 1024 + (lane << 4)),
          16, 0, 0);
    }
    __syncthreads();
#pragma unroll
    for (int kk = 0; kk < 2; ++kk) {
      const int gk = kk * 4 + (lane >> 4);
      bf16x8 av[4], bv[4];
#pragma unroll
      for (int mi = 0; mi < 4; ++mi) {
        const int r = wr * 64 + mi * 16 + (lane & 15);
        av[mi] = *(const bf16x8*)(ldsA + r * 128 + ((gk ^ (r & 7)) << 4));
      }
#pragma unroll
      for (int ni = 0; ni < 4; ++ni) {
        const int r = wc * 64 + ni * 16 + (lane & 15);
        bv[ni] = *(const bf16x8*)(ldsB + r * 128 + ((gk ^ (r & 7)) << 4));
      }
#pragma unroll
      for (int mi = 0; mi < 4; ++mi)
#pragma unroll
        for (int ni = 0; ni < 4; ++ni)
          acc[mi][ni] = __builtin_amdgcn_mfma_f32_16x16x32_bf16(av[mi], bv[ni], acc[mi][ni], 0, 0, 0);
    }
    __syncthreads();
  }

  const int cl = lane & 15;
  const int rg = (lane >> 4) << 2;
#pragma unroll
  for (int mi = 0; mi < 4; ++mi) {
#pragma unroll
    for (int ni = 0; ni < 4; ++ni) {
      const int gr = m0 + wr * 64 + mi * 16 + rg;
      const int gc = n0 + wc * 64 + ni * 16 + cl;
      float v0 = acc[mi][ni][0], v1 = acc[mi][ni][1];
      float v2 = acc[mi][ni][2], v3 = acc[mi][ni][3];
      if (ADD) {
        v0 += bf2f(Qadd[(size_t)(gr + 0) * 512 + gc]);
        v1 += bf2f(Qadd[(size_t)(gr + 1) * 512 + gc]);
        v2 += bf2f(Qadd[(size_t)(gr + 2) * 512 + gc]);
        v3 += bf2f(Qadd[(size_t)(gr + 3) * 512 + gc]);
      }
      unsigned short h0 = f2bf(v0), h1 = f2bf(v1), h2 = f2bf(v2), h3 = f2bf(v3);
      Crm[(size_t)(gr + 0) * 512 + gc] = h0;
      Crm[(size_t)(gr + 1) * 512 + gc] = h1;
      Crm[(size_t)(gr + 2) * 512 + gc] = h2;
      Crm[(size_t)(gr + 3) * 512 + gc] = h3;
      if (WRITE_T) {
        us4 tvec;
        tvec[0] = h0; tvec[1] = h1; tvec[2] = h2; tvec[3] = h3;
        *(us4*)(Ct + (size_t)gc * 512 + gr) = tvec;
      }
    }
  }
}

// ---------------------------------------------------------------------------
// S[b] = Cmat[b] @ Bmat[b]^T  (per graph, 512x512x256, fp32)
// ---------------------------------------------------------------------------
__global__ __launch_bounds__(256) void gemm_nt_kernel(const float* __restrict__ Cm,
                                                      const float* __restrict__ Bm,
                                                      float* __restrict__ S) {
  const int b = blockIdx.y;
  const float* Ab = Cm + (size_t)b * LNODE * DSTATE;
  const float* Bb = Bm + (size_t)b * LNODE * DSTATE;
  float* Sb = S + ((size_t)b << 18);
  const int tile = blockIdx.x;
  const int m0 = (tile >> 2) << 7;
  const int n0 = (tile & 3) << 7;
  __shared__ float As[16][132];
  __shared__ float Bs[16][132];
  const int tid = threadIdx.x;
  const int tx = tid & 15, ty = tid >> 4;
  float acc[8][8] = {};
  for (int k0 = 0; k0 < DSTATE; k0 += 16) {
#pragma unroll
    for (int s = 0; s < 2; ++s) {
      int fid = tid + s * 256;
      int m = fid >> 2, kq = fid & 3;
      float4 a = *(const float4*)(Ab + (size_t)(m0 + m) * DSTATE + k0 + kq * 4);
      As[kq * 4 + 0][m] = a.x; As[kq * 4 + 1][m] = a.y;
      As[kq * 4 + 2][m] = a.z; As[kq * 4 + 3][m] = a.w;
      float4 bb = *(const float4*)(Bb + (size_t)(n0 + m) * DSTATE + k0 + kq * 4);
      Bs[kq * 4 + 0][m] = bb.x; Bs[kq * 4 + 1][m] = bb.y;
      Bs[kq * 4 + 2][m] = bb.z; Bs[kq * 4 + 3][m] = bb.w;
    }
    __syncthreads();
#pragma unroll
    for (int k = 0; k < 16; ++k) {
      float av[8], bv[8];
      *(float4*)(av)     = *(const float4*)(&As[k][ty * 8]);
      *(float4*)(av + 4) = *(const float4*)(&As[k][ty * 8 + 4]);
      *(float4*)(bv)     = *(const float4*)(&Bs[k][tx * 8]);
      *(float4*)(bv + 4) = *(const float4*)(&Bs[k][tx * 8 + 4]);
#pragma unroll
      for (int i = 0; i < 8; ++i)
#pragma unroll
        for (int j = 0; j < 8; ++j)
          acc[i][j] = fmaf(av[i], bv[j], acc[i][j]);
    }
    __syncthreads();
  }
#pragma unroll
  for (int i = 0; i < 8; ++i) {
    size_t row = (size_t)(m0 + ty * 8 + i);
    float* sp = Sb + row * 512 + n0 + tx * 8;
    *(float4*)sp = make_float4(acc[i][0], acc[i][1], acc[i][2], acc[i][3]);
    *(float4*)(sp + 4) = make_float4(acc[i][4], acc[i][5], acc[i][6], acc[i][7]);
  }
}

// ---------------------------------------------------------------------------
// M = bf2f(Lm) * dt_self[t] * S[b,l,t]  -> fp32
// ---------------------------------------------------------------------------
__global__ void make_M_kernel(const unsigned short* __restrict__ Lm,
                              const float* __restrict__ S,
                              const float* __restrict__ dt,
                              float* __restrict__ M) {
  size_t idx = (size_t)blockIdx.x * blockDim.x + threadIdx.x;  // 32*512*512
  int t = (int)(idx & 511);
  size_t r = idx >> 9;
  int l = (int)(r & 511);
  int bn = (int)(r >> 9);
  int n = bn & 3, b = bn >> 2;
  float dts = dt[(size_t)(b * 512 + t) * 16 + n * 4 + 3];
  float s = S[((size_t)b << 18) + ((size_t)l << 9) + t];
  M[idx] = bf2f(Lm[idx]) * dts * s;
}

// ---------------------------------------------------------------------------
// out[(b*512+l)*256 + h*4 + n] = sum_t M[bn][l][t] * x[(b*512+t)*256 + n*64+h]
//                                + x[(b*512+l)*256 + n*64+h] * D[n]
// ---------------------------------------------------------------------------
__global__ __launch_bounds__(256) void final_gemm_kernel(const float* __restrict__ M,
                                                         const float* __restrict__ x,
                                                         const float* __restrict__ Dv,
                                                         float* __restrict__ out) {
  const int bn = blockIdx.y;
  const int n = bn & 3, b = bn >> 2;
  const float* Mb = M + ((size_t)bn << 18);
  const float* xb = x + (size_t)b * LNODE * DINNER + n * HEADD;
  const int m0 = blockIdx.x << 7;
  __shared__ float Ms[16][132];
  __shared__ float Xs[16][64];
  const int tid = threadIdx.x;
  const int tx = tid & 15, ty = tid >> 4;
  float acc[8][4] = {};
  for (int k0 = 0; k0 < 512; k0 += 16) {
#pragma unroll
    for (int s = 0; s < 2; ++s) {
      int fid = tid + s * 256;
      int m = fid >> 2, kq = fid & 3;
      float4 a = *(const float4*)(Mb + (size_t)(m0 + m) * 512 + k0 + kq * 4);
      Ms[kq * 4 + 0][m] = a.x; Ms[kq * 4 + 1][m] = a.y;
      Ms[kq * 4 + 2][m] = a.z; Ms[kq * 4 + 3][m] = a.w;
    }
    {
      int kk = tid >> 4, hq = tid & 15;
      float4 v = *(const float4*)(xb + (size_t)(k0 + kk) * DINNER + hq * 4);
      *(float4*)(&Xs[kk][hq * 4]) = v;
    }
    __syncthreads();
#pragma unroll
    for (int k = 0; k < 16; ++k) {
      float mv[8], xv[4];
      *(float4*)(mv)     = *(const float4*)(&Ms[k][ty * 8]);
      *(float4*)(mv + 4) = *(const float4*)(&Ms[k][ty * 8 + 4]);
      *(float4*)(xv)     = *(const float4*)(&Xs[k][tx * 4]);
#pragma unroll
      for (int i = 0; i < 8; ++i)
#pragma unroll
        for (int j = 0; j < 4; ++j)
          acc[i][j] = fmaf(mv[i], xv[j], acc[i][j]);
    }
    __syncthreads();
  }
  const float Dn = Dv[n];
#pragma unroll
  for (int i = 0; i < 8; ++i) {
    const int l = m0 + ty * 8 + i;
    const float* xrow = x + (size_t)(b * LNODE + l) * DINNER + n * HEADD;
    float* orow = out + (size_t)(b * LNODE + l) * DINNER + n;
#pragma unroll
    for (int j = 0; j < 4; ++j) {
      const int h = tx * 4 + j;
      orow[h * 4] = acc[i][j] + xrow[h] * Dn;
    }
  }
}

// ---------------------------------------------------------------------------
extern "C" void kernel_launch(void* const* d_in, const int* in_sizes, int n_in,
                              void* d_out, int out_size, void* d_ws, size_t ws_size,
                              hipStream_t stream) {
  const float* x        = (const float*)d_in[0];
  const float* Bmat     = (const float*)d_in[1];
  const float* Cmat     = (const float*)d_in[2];
  const float* dt       = (const float*)d_in[3];
  const float* dt_edge  = (const float*)d_in[4];
  const float* dt_bias  = (const float*)d_in[5];
  const float* Dv       = (const float*)d_in[6];
  const int* edge_index = (const int*)d_in[7];
  float* out = (float*)d_out;

  // Workspace map (100.7 MB total):
  //  [0, 32M)    : G fp32  -> later F_rm/F_t bf16 pair (R0a,R0b) -> later M fp32
  //  [32M, 48M)  : S2 bf16 slot  (later Sbuf fp32, 8 MB)
  //  [48M, 64M)  : S3 bf16 slot
  //  [64M, 80M)  : S4 bf16 slot
  //  [80M, 96M)  : S5 bf16 slot
  char* wsb = (char*)d_ws;
  float* G = (float*)wsb;
  unsigned short* R0a = (unsigned short*)wsb;
  unsigned short* R0b = (unsigned short*)(wsb + 16777216);
  unsigned short* S2  = (unsigned short*)(wsb + 33554432);
  unsigned short* S3  = (unsigned short*)(wsb + 50331648);
  unsigned short* S4  = (unsigned short*)(wsb + 67108864);
  unsigned short* S5  = (unsigned short*)(wsb + 83886080);
  float* Sbuf = (float*)(wsb + 33554432);
  float* M    = (float*)wsb;

  hipMemsetAsync(G, 0, 33554432, stream);
  scatter_edges_kernel<<<1024, 256, 0, stream>>>(dt, dt_edge, dt_bias, edge_index, G);
  col_normalize_kernel<<<64, 256, 0, stream>>>(G, dt, dt_bias);
  conv_kernel<<<dim3(256, 32), 256, 0, stream>>>(G, S2, S3, S4);  // P_rm, P_t, Q

  dim3 gg(16, 32);
  // iter0: F = P@P ; Qn = Q@F + Q
  gemm_bf16_kernel<true,  false><<<gg, 256, 0, stream>>>(S2, S3, R0a, R0b, nullptr);
  gemm_bf16_kernel<false, true ><<<gg, 256, 0, stream>>>(S4, R0b, S5, nullptr, S4);
  // iter1
  gemm_bf16_kernel<true,  false><<<gg, 256, 0, stream>>>(R0a, R0b, S2, S3, nullptr);
  gemm_bf16_kernel<false, true ><<<gg, 256, 0, stream>>>(S5, S3, S4, nullptr, S5);
  // iter2
  gemm_bf16_kernel<true,  false><<<gg, 256, 0, stream>>>(S2, S3, R0a, R0b, nullptr);
  gemm_bf16_kernel<false, true ><<<gg, 256, 0, stream>>>(S4, R0b, S5, nullptr, S4);
  // iter3 -> Lm in S4
  gemm_bf16_kernel<true,  false><<<gg, 256, 0, stream>>>(R0a, R0b, S2, S3, nullptr);
  gemm_bf16_kernel<false, true ><<<gg, 256, 0, stream>>>(S5, S3, S4, nullptr, S5);

  gemm_nt_kernel<<<dim3(16, 8), 256, 0, stream>>>(Cmat, Bmat, Sbuf);
  make_M_kernel<<<32768, 256, 0, stream>>>(S4, Sbuf, dt, M);
  final_gemm_kernel<<<dim3(4, 32), 256, 0, stream>>>(M, x, Dv, out);
}

// Round 3
// 324.518 us; speedup vs baseline: 3.3705x; 1.2983x over previous
//
#include <hip/hip_runtime.h>
#include <math.h>

#define N_EDGES 65536
#define LNODE 512
#define DSTATE 256
#define DINNER 256
#define HEADD 64

using bf16x8 = __attribute__((ext_vector_type(8))) short;
using f32x4  = __attribute__((ext_vector_type(4))) float;
using us4    = __attribute__((ext_vector_type(4))) unsigned short;

__device__ __forceinline__ float softplusf(float z) {
  return (z > 0.0f) ? (z + log1pf(expf(-z))) : log1pf(expf(z));
}
__device__ __forceinline__ float bf2f(unsigned short u) {
  unsigned int x = ((unsigned int)u) << 16;
  return __builtin_bit_cast(float, x);
}
__device__ __forceinline__ unsigned short f2bf(float f) {
  unsigned int x = __builtin_bit_cast(unsigned int, f);
  x += 0x7fffu + ((x >> 16) & 1u);
  return (unsigned short)(x >> 16);
}

// ---------------------------------------------------------------------------
// Scatter edges into G = A^T (per (graph,head) 512x512), G[l2][l1] += val,
// and accumulate column sums colsum[bn][l1] += val (kills the old 90us
// column-walk normalize kernel).
// ---------------------------------------------------------------------------
__global__ void scatter_edges_kernel(const float* __restrict__ dt,
                                     const float* __restrict__ dt_edge,
                                     const float* __restrict__ dt_bias,
                                     const int* __restrict__ edge_index,
                                     float* __restrict__ G,
                                     float* __restrict__ colsum) {
  int t = blockIdx.x * blockDim.x + threadIdx.x;
  if (t >= N_EDGES * 4) return;
  int e = t >> 2;
  int n = t & 3;
  int src = edge_index[e];
  int dst = edge_index[N_EDGES + e];
  float bias = dt_bias[n];
  float z0 = dt[src * 16 + n * 4 + 0] + bias;
  float z1 = dt[dst * 16 + n * 4 + 1] + bias;
  float z2 = dt_edge[e * 4 + n] + bias;
  float val = expf(-(softplusf(z0) + softplusf(z1) + softplusf(z2)) * (1.0f / 3.0f));
  int b = src >> 9;
  int l1 = src & 511;
  int l2 = dst & 511;
  int bn = b * 4 + n;
  atomicAdd(&G[(((size_t)bn) << 18) + ((size_t)l2 << 9) + l1], val);
  atomicAdd(&colsum[bn * 512 + l1], val);
}

// ---------------------------------------------------------------------------
// Convert + normalize: v = G * inv(col); Prm = bf16(v), Pt = bf16(v^T),
// Q = bf16(I + v). 32x32 tiles, per-column inv computed once into LDS.
// ---------------------------------------------------------------------------
__global__ __launch_bounds__(256) void conv_kernel(const float* __restrict__ G,
                                                   const float* __restrict__ colsum,
                                                   const float* __restrict__ dt,
                                                   const float* __restrict__ dt_bias,
                                                   unsigned short* __restrict__ Prm,
                                                   unsigned short* __restrict__ Pt,
                                                   unsigned short* __restrict__ Q) {
  const int bn = blockIdx.y;
  const int n = bn & 3, b = bn >> 2;
  const size_t base = (size_t)bn << 18;
  const int tile = blockIdx.x;
  const int ro = (tile >> 4) << 5;
  const int co = (tile & 15) << 5;
  __shared__ float lds[32][33];
  __shared__ float sinv[32];
  const int t = threadIdx.x;
  if (t < 32) {
    const int col = co + t;
    float ssum = colsum[bn * 512 + col];
    float bias = dt_bias[n];
    float dummy = expf(-softplusf(dt[(size_t)(b * 512 + col) * 16 + n * 4 + 2] + bias));
    float norm = fmaxf(1.0f, ssum + dummy);
    sinv[t] = 1.0f / (norm + 0.05f);
  }
  __syncthreads();
  const int tr = t >> 3;
  const int tc0 = (t & 7) << 2;
  float4 gv = *(const float4*)(G + base + (size_t)(ro + tr) * 512 + co + tc0);
  float vv[4] = {gv.x, gv.y, gv.z, gv.w};
  us4 p, q;
#pragma unroll
  for (int j = 0; j < 4; ++j) {
    vv[j] *= sinv[tc0 + j];
    p[j] = f2bf(vv[j]);
    float qq = vv[j] + (((ro + tr) == (co + tc0 + j)) ? 1.0f : 0.0f);
    q[j] = f2bf(qq);
    lds[tc0 + j][tr] = vv[j];
  }
  *(us4*)(Prm + base + (size_t)(ro + tr) * 512 + co + tc0) = p;
  *(us4*)(Q + base + (size_t)(ro + tr) * 512 + co + tc0) = q;
  __syncthreads();
  us4 pt;
#pragma unroll
  for (int j = 0; j < 4; ++j) pt[j] = f2bf(lds[tr][tc0 + j]);
  *(us4*)(Pt + base + (size_t)(co + tr) * 512 + ro + tc0) = pt;
}

// ---------------------------------------------------------------------------
// Batched bf16 MFMA GEMM: C = A @ B (+ Qadd), B given transposed ([N][K]).
// 128x128 tile, BK=64, 4 waves, global_load_lds staging, XOR-swizzled LDS.
// Optionally writes C row-major and/or C^T. 32 batches of 512x512x512.
// ---------------------------------------------------------------------------
template <bool WRITE_RM, bool WRITE_T, bool ADD>
__global__ __launch_bounds__(256) void gemm_bf16_kernel(
    const unsigned short* __restrict__ A, const unsigned short* __restrict__ Bt,
    unsigned short* __restrict__ Crm, unsigned short* __restrict__ Ct,
    const unsigned short* __restrict__ Qadd) {
  const int bn = blockIdx.y;
  const size_t off = (size_t)bn << 18;
  A += off; Bt += off;
  if (WRITE_RM) Crm += off;
  if (WRITE_T) Ct += off;
  if (ADD) Qadd += off;
  const int m0 = (blockIdx.x >> 2) << 7;
  const int n0 = (blockIdx.x & 3) << 7;
  __shared__ __align__(16) char lds[32768];
  char* ldsA = lds;
  char* ldsB = lds + 16384;
  const int tid = threadIdx.x;
  const int lane = tid & 63;
  const int w = tid >> 6;
  const int wr = w >> 1, wc = w & 1;
  const int lr = lane >> 3, g = lane & 7;

  f32x4 acc[4][4];
#pragma unroll
  for (int i = 0; i < 4; ++i)
#pragma unroll
    for (int j = 0; j < 4; ++j) acc[i][j] = (f32x4)(0.0f);

  for (int k0 = 0; k0 < 512; k0 += 64) {
#pragma unroll
    for (int s = 0; s < 4; ++s) {
      const int r = s * 32 + w * 8 + lr;
      const unsigned short* ga = A + (size_t)(m0 + r) * 512 + k0 + ((g ^ (r & 7)) << 3);
      __builtin_amdgcn_global_load_lds(
          (const __attribute__((address_space(1))) void*)ga,
          (__attribute__((address_space(3))) void*)(ldsA + s * 4096 + w * 1024 + (lane << 4)),
          16, 0, 0);
      const unsigned short* gb = Bt + (size_t)(n0 + r) * 512 + k0 + ((g ^ (r & 7)) << 3);
      __builtin_amdgcn_global_load_lds(
          (const __attribute__((address_space(1))) void*)gb,
          (__attribute__((address_space(3))) void*)(ldsB + s * 4096 + w * 1024 + (lane << 4)),
          16, 0, 0);
    }
    __syncthreads();
#pragma unroll
    for (int kk = 0; kk < 2; ++kk) {
      const int gk = kk * 4 + (lane >> 4);
      bf16x8 av[4], bv[4];
#pragma unroll
      for (int mi = 0; mi < 4; ++mi) {
        const int r = wr * 64 + mi * 16 + (lane & 15);
        av[mi] = *(const bf16x8*)(ldsA + r * 128 + ((gk ^ (r & 7)) << 4));
      }
#pragma unroll
      for (int ni = 0; ni < 4; ++ni) {
        const int r = wc * 64 + ni * 16 + (lane & 15);
        bv[ni] = *(const bf16x8*)(ldsB + r * 128 + ((gk ^ (r & 7)) << 4));
      }
#pragma unroll
      for (int mi = 0; mi < 4; ++mi)
#pragma unroll
        for (int ni = 0; ni < 4; ++ni)
          acc[mi][ni] = __builtin_amdgcn_mfma_f32_16x16x32_bf16(av[mi], bv[ni], acc[mi][ni], 0, 0, 0);
    }
    __syncthreads();
  }

  const int cl = lane & 15;
  const int rg = (lane >> 4) << 2;
#pragma unroll
  for (int mi = 0; mi < 4; ++mi) {
#pragma unroll
    for (int ni = 0; ni < 4; ++ni) {
      const int gr = m0 + wr * 64 + mi * 16 + rg;
      const int gc = n0 + wc * 64 + ni * 16 + cl;
      float v0 = acc[mi][ni][0], v1 = acc[mi][ni][1];
      float v2 = acc[mi][ni][2], v3 = acc[mi][ni][3];
      if (ADD) {
        v0 += bf2f(Qadd[(size_t)(gr + 0) * 512 + gc]);
        v1 += bf2f(Qadd[(size_t)(gr + 1) * 512 + gc]);
        v2 += bf2f(Qadd[(size_t)(gr + 2) * 512 + gc]);
        v3 += bf2f(Qadd[(size_t)(gr + 3) * 512 + gc]);
      }
      unsigned short h0 = f2bf(v0), h1 = f2bf(v1), h2 = f2bf(v2), h3 = f2bf(v3);
      if (WRITE_RM) {
        Crm[(size_t)(gr + 0) * 512 + gc] = h0;
        Crm[(size_t)(gr + 1) * 512 + gc] = h1;
        Crm[(size_t)(gr + 2) * 512 + gc] = h2;
        Crm[(size_t)(gr + 3) * 512 + gc] = h3;
      }
      if (WRITE_T) {
        us4 tvec;
        tvec[0] = h0; tvec[1] = h1; tvec[2] = h2; tvec[3] = h3;
        *(us4*)(Ct + (size_t)gc * 512 + gr) = tvec;
      }
    }
  }
}

// ---------------------------------------------------------------------------
// S[b] = Cmat[b] @ Bmat[b]^T  (per graph, 512x512x256, fp32)
// ---------------------------------------------------------------------------
__global__ __launch_bounds__(256) void gemm_nt_kernel(const float* __restrict__ Cm,
                                                      const float* __restrict__ Bm,
                                                      float* __restrict__ S) {
  const int b = blockIdx.y;
  const float* Ab = Cm + (size_t)b * LNODE * DSTATE;
  const float* Bb = Bm + (size_t)b * LNODE * DSTATE;
  float* Sb = S + ((size_t)b << 18);
  const int tile = blockIdx.x;
  const int m0 = (tile >> 2) << 7;
  const int n0 = (tile & 3) << 7;
  __shared__ float As[16][132];
  __shared__ float Bs[16][132];
  const int tid = threadIdx.x;
  const int tx = tid & 15, ty = tid >> 4;
  float acc[8][8] = {};
  for (int k0 = 0; k0 < DSTATE; k0 += 16) {
#pragma unroll
    for (int s = 0; s < 2; ++s) {
      int fid = tid + s * 256;
      int m = fid >> 2, kq = fid & 3;
      float4 a = *(const float4*)(Ab + (size_t)(m0 + m) * DSTATE + k0 + kq * 4);
      As[kq * 4 + 0][m] = a.x; As[kq * 4 + 1][m] = a.y;
      As[kq * 4 + 2][m] = a.z; As[kq * 4 + 3][m] = a.w;
      float4 bb = *(const float4*)(Bb + (size_t)(n0 + m) * DSTATE + k0 + kq * 4);
      Bs[kq * 4 + 0][m] = bb.x; Bs[kq * 4 + 1][m] = bb.y;
      Bs[kq * 4 + 2][m] = bb.z; Bs[kq * 4 + 3][m] = bb.w;
    }
    __syncthreads();
#pragma unroll
    for (int k = 0; k < 16; ++k) {
      float av[8], bv[8];
      *(float4*)(av)     = *(const float4*)(&As[k][ty * 8]);
      *(float4*)(av + 4) = *(const float4*)(&As[k][ty * 8 + 4]);
      *(float4*)(bv)     = *(const float4*)(&Bs[k][tx * 8]);
      *(float4*)(bv + 4) = *(const float4*)(&Bs[k][tx * 8 + 4]);
#pragma unroll
      for (int i = 0; i < 8; ++i)
#pragma unroll
        for (int j = 0; j < 8; ++j)
          acc[i][j] = fmaf(av[i], bv[j], acc[i][j]);
    }
    __syncthreads();
  }
#pragma unroll
  for (int i = 0; i < 8; ++i) {
    size_t row = (size_t)(m0 + ty * 8 + i);
    float* sp = Sb + row * 512 + n0 + tx * 8;
    *(float4*)sp = make_float4(acc[i][0], acc[i][1], acc[i][2], acc[i][3]);
    *(float4*)(sp + 4) = make_float4(acc[i][4], acc[i][5], acc[i][6], acc[i][7]);
  }
}

// ---------------------------------------------------------------------------
// Fused make_M + final GEMM:
// out[(b*512+l)*256 + h*4 + n] =
//   sum_t (bf2f(Lm[bn][l][t]) * dts[t] * S[b][l][t]) * x[(b*512+t)*256+n*64+h]
//   + x[(b*512+l)*256+n*64+h] * D[n]
// ---------------------------------------------------------------------------
__global__ __launch_bounds__(256) void final_fused_kernel(
    const unsigned short* __restrict__ Lm, const float* __restrict__ S,
    const float* __restrict__ dt, const float* __restrict__ x,
    const float* __restrict__ Dv, float* __restrict__ out) {
  const int bn = blockIdx.y;
  const int n = bn & 3, b = bn >> 2;
  const unsigned short* Lb = Lm + ((size_t)bn << 18);
  const float* Sb = S + ((size_t)b << 18);
  const float* xb = x + (size_t)b * LNODE * DINNER + n * HEADD;
  const int m0 = blockIdx.x << 7;
  __shared__ float Ms[16][132];
  __shared__ float Xs[16][64];
  __shared__ float dts_all[512];
  const int tid = threadIdx.x;
  const int tx = tid & 15, ty = tid >> 4;
  for (int i = tid; i < 512; i += 256)
    dts_all[i] = dt[(size_t)(b * 512 + i) * 16 + n * 4 + 3];
  __syncthreads();
  float acc[8][4] = {};
  for (int k0 = 0; k0 < 512; k0 += 16) {
#pragma unroll
    for (int s = 0; s < 2; ++s) {
      int fid = tid + s * 256;
      int m = fid >> 2, kq = fid & 3;
      us4 lm = *(const us4*)(Lb + (size_t)(m0 + m) * 512 + k0 + kq * 4);
      float4 sv = *(const float4*)(Sb + (size_t)(m0 + m) * 512 + k0 + kq * 4);
      Ms[kq * 4 + 0][m] = bf2f(lm[0]) * sv.x * dts_all[k0 + kq * 4 + 0];
      Ms[kq * 4 + 1][m] = bf2f(lm[1]) * sv.y * dts_all[k0 + kq * 4 + 1];
      Ms[kq * 4 + 2][m] = bf2f(lm[2]) * sv.z * dts_all[k0 + kq * 4 + 2];
      Ms[kq * 4 + 3][m] = bf2f(lm[3]) * sv.w * dts_all[k0 + kq * 4 + 3];
    }
    {
      int kk = tid >> 4, hq = tid & 15;
      float4 v = *(const float4*)(xb + (size_t)(k0 + kk) * DINNER + hq * 4);
      *(float4*)(&Xs[kk][hq * 4]) = v;
    }
    __syncthreads();
#pragma unroll
    for (int k = 0; k < 16; ++k) {
      float mv[8], xv[4];
      *(float4*)(mv)     = *(const float4*)(&Ms[k][ty * 8]);
      *(float4*)(mv + 4) = *(const float4*)(&Ms[k][ty * 8 + 4]);
      *(float4*)(xv)     = *(const float4*)(&Xs[k][tx * 4]);
#pragma unroll
      for (int i = 0; i < 8; ++i)
#pragma unroll
        for (int j = 0; j < 4; ++j)
          acc[i][j] = fmaf(mv[i], xv[j], acc[i][j]);
    }
    __syncthreads();
  }
  const float Dn = Dv[n];
#pragma unroll
  for (int i = 0; i < 8; ++i) {
    const int l = m0 + ty * 8 + i;
    const float* xrow = x + (size_t)(b * LNODE + l) * DINNER + n * HEADD;
    float* orow = out + (size_t)(b * LNODE + l) * DINNER + n;
#pragma unroll
    for (int j = 0; j < 4; ++j) {
      const int h = tx * 4 + j;
      orow[h * 4] = acc[i][j] + xrow[h] * Dn;
    }
  }
}

// ---------------------------------------------------------------------------
extern "C" void kernel_launch(void* const* d_in, const int* in_sizes, int n_in,
                              void* d_out, int out_size, void* d_ws, size_t ws_size,
                              hipStream_t stream) {
  const float* x        = (const float*)d_in[0];
  const float* Bmat     = (const float*)d_in[1];
  const float* Cmat     = (const float*)d_in[2];
  const float* dt       = (const float*)d_in[3];
  const float* dt_edge  = (const float*)d_in[4];
  const float* dt_bias  = (const float*)d_in[5];
  const float* Dv       = (const float*)d_in[6];
  const int* edge_index = (const int*)d_in[7];
  float* out = (float*)d_out;

  // Workspace map (~100.8 MB):
  //  [0, 32M)    : G fp32  -> later F_rm/F_t bf16 pair (R0a,R0b)
  //  [32M, 48M)  : S2 bf16 slot  (later Sbuf fp32, 8.4 MB)
  //  [48M, 64M)  : S3 bf16 slot
  //  [64M, 80M)  : S4 bf16 slot
  //  [80M, 96M)  : S5 bf16 slot
  //  [96M, +64K) : colsum fp32
  char* wsb = (char*)d_ws;
  float* G = (float*)wsb;
  unsigned short* R0a = (unsigned short*)wsb;
  unsigned short* R0b = (unsigned short*)(wsb + 16777216);
  unsigned short* S2  = (unsigned short*)(wsb + 33554432);
  unsigned short* S3  = (unsigned short*)(wsb + 50331648);
  unsigned short* S4  = (unsigned short*)(wsb + 67108864);
  unsigned short* S5  = (unsigned short*)(wsb + 83886080);
  float* Sbuf   = (float*)(wsb + 33554432);
  float* colsum = (float*)(wsb + 100663296);

  hipMemsetAsync(G, 0, 33554432, stream);
  hipMemsetAsync(colsum, 0, 32 * 512 * 4, stream);
  scatter_edges_kernel<<<1024, 256, 0, stream>>>(dt, dt_edge, dt_bias, edge_index, G, colsum);
  conv_kernel<<<dim3(256, 32), 256, 0, stream>>>(G, colsum, dt, dt_bias, S2, S3, S4);  // P_rm, P_t, Q

  dim3 gg(16, 32);
  // iter0: F = P@P ; Qn = Q@F + Q
  gemm_bf16_kernel<true,  true,  false><<<gg, 256, 0, stream>>>(S2, S3, R0a, R0b, nullptr);
  gemm_bf16_kernel<true,  false, true ><<<gg, 256, 0, stream>>>(S4, R0b, S5, nullptr, S4);
  // iter1
  gemm_bf16_kernel<true,  true,  false><<<gg, 256, 0, stream>>>(R0a, R0b, S2, S3, nullptr);
  gemm_bf16_kernel<true,  false, true ><<<gg, 256, 0, stream>>>(S5, S3, S4, nullptr, S5);
  // iter2
  gemm_bf16_kernel<true,  true,  false><<<gg, 256, 0, stream>>>(S2, S3, R0a, R0b, nullptr);
  gemm_bf16_kernel<true,  false, true ><<<gg, 256, 0, stream>>>(S4, R0b, S5, nullptr, S4);
  // iter3 (squaring writes only F^T; row-major F unused)
  gemm_bf16_kernel<false, true,  false><<<gg, 256, 0, stream>>>(R0a, R0b, nullptr, S3, nullptr);
  gemm_bf16_kernel<true,  false, true ><<<gg, 256, 0, stream>>>(S5, S3, S4, nullptr, S5);
  // Lm in S4

  gemm_nt_kernel<<<dim3(16, 8), 256, 0, stream>>>(Cmat, Bmat, Sbuf);
  final_fused_kernel<<<dim3(4, 32), 256, 0, stream>>>(S4, Sbuf, dt, x, Dv, out);
}